// Round 1
// baseline (273.674 us; speedup 1.0000x reference)
//
#include <hip/hip_runtime.h>

// VectorQuantiser forward, MI355X fp32.
// N=65536 tokens (16x64x64, channel dim 64 strided by 4096), K=1024 codes, D=64.
//
// Round 3: z pinned in VGPRs via empty inline-asm (round-2 counters showed
// VGPR_Count=52 => compiler sank the z loads into the code loop; kernel was
// L1-throughput-bound at VALUBusy=45%). launch_bounds(256,3) gives the
// allocator ~170 VGPRs of headroom (z[64] + ~40 overhead, no spill).
// #pragma unroll 2 on the code loop overlaps e-row s_loads with FMAs.
// k_scalars merged into k_newemb (-> k_tail) to drop one launch gap.
// All rounding-sensitive fp ops kept bit-identical to the passing code.

#define KP 4

// ---- ws layout (bytes) ----
#define WS_ROW   0        // u64 wsrow[65536]  packed (ord(d)<<32)|~k
#define WS_COL   524288   // u64 wscol[1024]   packed (ord(d)<<32)|~n
#define WS_CNT   532480   // u32 counts[1024]
#define WS_LOSS  536576   // double loss_acc
#define WS_EN2   536592   // float en2[1024]
#define WS_BYTES 540688

__device__ __forceinline__ unsigned int f32_ord(float x) {
    unsigned int b = __float_as_uint(x);
    return (b & 0x80000000u) ? ~b : (b | 0x80000000u);
}

// numpy pairwise sum of squares over 64 contiguous values (8 strided chains,
// then ((r0+r1)+(r2+r3))+((r4+r5)+(r6+r7))), fp32, no contraction.
template <typename F>
__device__ __forceinline__ float np_pairwise64_sq(F get) {
    float r[8];
#pragma unroll
    for (int j = 0; j < 8; ++j) {
        float v = get(j);
        r[j] = __fmul_rn(v, v);
    }
#pragma unroll
    for (int i = 8; i < 64; i += 8) {
#pragma unroll
        for (int j = 0; j < 8; ++j) {
            float v = get(i + j);
            r[j] = __fadd_rn(r[j], __fmul_rn(v, v));
        }
    }
    return __fadd_rn(__fadd_rn(__fadd_rn(r[0], r[1]), __fadd_rn(r[2], r[3])),
                     __fadd_rn(__fadd_rn(r[4], r[5]), __fadd_rn(r[6], r[7])));
}

// ---- K0: codebook squared norms ----
__global__ __launch_bounds__(256) void k_en2(const float* __restrict__ emb,
                                             float* __restrict__ en2) {
    int k = blockIdx.x * 256 + threadIdx.x;
    const float* a = emb + (size_t)k * 64;
    en2[k] = np_pairwise64_sq([&](int i) { return a[i]; });
}

// ---- K1: score matrix + row/col argmax ----
// grid (256 token-blocks, KP code-partitions), block 256 = 4 waves.
// Thread = 1 token (z pinned in 64 VGPRs). Embedding reads wave-uniform ->
// s_load (SGPR operand feeds v_fma directly; no VMEM in the inner loop).
// Column argmax: per-wave LDS tile [64 tokens][32 codes], stride 33.
__global__ __launch_bounds__(256, 3) void k_scores(
    const float* __restrict__ z, const float* __restrict__ emb,
    const float* __restrict__ en2,
    unsigned long long* __restrict__ wsrow,
    unsigned long long* __restrict__ wscol) {
    const int t    = threadIdx.x;
    const int lane = t & 63;
    const int wave = t >> 6;
    const int n    = blockIdx.x * 256 + t;
    const int k0   = blockIdx.y * 256;
    const int b    = n >> 12;
    const int hw   = n & 4095;

    __shared__ float tile[4][64 * 33];            // 33792 B, per-wave slabs
    __shared__ unsigned long long kbuf[4][32];    // 1 KB

    const float* zp = z + (size_t)b * 262144 + hw;
    float zr[64];
#pragma unroll
    for (int c = 0; c < 64; ++c) zr[c] = zp[(size_t)c * 4096];
    // Pin z in VGPRs: the compiler cannot rematerialize an asm result, so the
    // 256 code-iterations below must read these registers instead of
    // re-fetching z from L1 per code (round-2 counters: VGPR_Count=52,
    // VALUBusy=45% => the loads had been sunk into the inner loop).
#pragma unroll
    for (int c = 0; c < 64; ++c) asm("" : "+v"(zr[c]));

    const float nzn2 = -np_pairwise64_sq([&](int i) { return zr[i]; });

    float bestv = -3.4e38f;
    int   bestk = k0;

    const float4* E4 = reinterpret_cast<const float4*>(emb);
    float* mytile = tile[wave];

    for (int g = 0; g < 8; ++g) {
        const int kg = k0 + g * 32;

#pragma unroll 2
        for (int kk = 0; kk < 32; ++kk) {
            const int k = kg + kk;
            const float4* ek = E4 + (size_t)k * 16;   // wave-uniform -> s_load
            float c0 = 0.f, c1 = 0.f, c2 = 0.f, c3 = 0.f;
#pragma unroll
            for (int j = 0; j < 16; ++j) {
                float4 e = ek[j];
                c0 = fmaf(e.x, zr[4 * j + 0], c0);
                c1 = fmaf(e.y, zr[4 * j + 1], c1);
                c2 = fmaf(e.z, zr[4 * j + 2], c2);
                c3 = fmaf(e.w, zr[4 * j + 3], c3);
            }
            float dot = (c0 + c1) + (c2 + c3);
            // d = ((-zn2) - en2) + 2*dot, per-op fp32 like numpy
            float d = __fadd_rn(__fsub_rn(nzn2, en2[k]), 2.0f * dot);

            // row argmax: ascending k, strict > == first-index ties
            if (d > bestv) { bestv = d; bestk = k; }

            // stash for column reduction: bank (lane+kk)&31 -> 2-way, free
            mytile[lane * 33 + kk] = d;
        }
        __syncthreads();  // also orders tile writes vs cross-lane reads

        // column reduce: lane owns code c=lane&31, half h=lane>>5 (32 tokens)
        {
            const int c = lane & 31, h = lane >> 5;
            const float* col = mytile + (h * 32) * 33 + c;
            float bv = col[0];
            int   bt = 0;
#pragma unroll
            for (int tt = 1; tt < 32; ++tt) {
                float v = col[(size_t)tt * 33];
                if (v > bv) { bv = v; bt = tt; }   // ascending token, strict >
            }
            int nwin = blockIdx.x * 256 + wave * 64 + h * 32 + bt;
            unsigned long long key =
                ((unsigned long long)f32_ord(bv) << 32) |
                (unsigned long long)(unsigned int)(~(unsigned int)nwin);
            unsigned long long other = __shfl_xor(key, 32, 64);
            if (other > key) key = other;          // ties: larger key = smaller n
            if (h == 0) kbuf[wave][c] = key;
        }
        __syncthreads();
        if (t < 32) {
            unsigned long long m = kbuf[0][t];
#pragma unroll
            for (int w = 1; w < 4; ++w) {
                unsigned long long o = kbuf[w][t];
                m = (o > m) ? o : m;
            }
            atomicMax(&wscol[kg + t], m);
        }
        __syncthreads();
    }

    unsigned long long rowkey =
        ((unsigned long long)f32_ord(bestv) << 32) |
        (unsigned long long)(unsigned int)(~(unsigned int)bestk);
    atomicMax(&wsrow[n], rowkey);
}

// ---- K2: per-token outputs: z_q (straight-through), indices, hist, loss ----
__global__ __launch_bounds__(256) void k_tokens(
    const float* __restrict__ z, const float* __restrict__ emb,
    const unsigned long long* __restrict__ wsrow,
    unsigned int* __restrict__ counts, double* __restrict__ loss_acc,
    float* __restrict__ out_zq, float* __restrict__ out_idx) {
    const int n  = blockIdx.x * 256 + threadIdx.x;
    const int b  = n >> 12;
    const int hw = n & 4095;

    unsigned long long key = wsrow[n];
    int idx = (int)(~(unsigned int)(key & 0xFFFFFFFFull));
    out_idx[n] = (float)idx;
    atomicAdd(&counts[idx], 1u);

    const float* zp = z + (size_t)b * 262144 + hw;
    float*       op = out_zq + (size_t)b * 262144 + hw;
    const float* ep = emb + (size_t)idx * 64;

    double ls = 0.0;
#pragma unroll
    for (int c = 0; c < 64; ++c) {
        float zc   = zp[(size_t)c * 4096];
        float eq   = ep[c];
        float diff = __fsub_rn(eq, zc);              // fl(z_q - zc)
        float sq   = __fmul_rn(diff, diff);
        ls += (double)sq;
        op[(size_t)c * 4096] = __fadd_rn(zc, diff);  // zc + fl(z_q - zc)
    }

    __shared__ double sred[256];
    sred[threadIdx.x] = ls;
    __syncthreads();
    for (int st = 128; st; st >>= 1) {
        if (threadIdx.x < st) sred[threadIdx.x] += sred[threadIdx.x + st];
        __syncthreads();
    }
    if (threadIdx.x == 0) atomicAdd(loss_acc, sred[0]);
}

// ---- K3: tail — new embedding (all blocks) + scalars (block 0 only) ----
// grid 64 x 1024 threads. newemb: thread = (code, channel), 16 codes/block.
// Block 0 additionally computes loss/perplexity/embed_prob (former k_scalars,
// code copied verbatim -> bit-identical).
__global__ __launch_bounds__(1024) void k_tail(
    const float* __restrict__ z, const float* __restrict__ emb,
    const float* __restrict__ embed_prob,
    const unsigned long long* __restrict__ wscol,
    const unsigned int* __restrict__ counts,
    const double* __restrict__ loss_acc,
    float* __restrict__ out_newemb, float* __restrict__ out_loss,
    float* __restrict__ out_perp, float* __restrict__ out_prob) {
    const int k = blockIdx.x * 16 + (threadIdx.x >> 6);
    const int c = threadIdx.x & 63;

    // recompute pnew/decay with ops identical to the scalars path (bit-equal)
    float avg  = (float)counts[k] * (1.0f / 65536.0f);
    float pnew = __fadd_rn(__fmul_rn(embed_prob[k], 0.99f),
                           __fmul_rn(0.01f, avg));
    float tt = __fdiv_rn(__fmul_rn(__fmul_rn(pnew, 1024.0f), 10.0f), 0.01f);
    float dk = expf(__fsub_rn(-tt, 1e-3f));
    float omd = __fsub_rn(1.0f, dk);

    unsigned long long ck = wscol[k];
    int cn  = (int)(~(unsigned int)(ck & 0xFFFFFFFFull));
    int cb  = cn >> 12;
    int chw = cn & 4095;

    float rf = z[(size_t)cb * 262144 + (size_t)c * 4096 + chw];
    float e  = emb[(size_t)k * 64 + c];
    out_newemb[(size_t)k * 64 + c] =
        __fadd_rn(__fmul_rn(e, omd), __fmul_rn(rf, dk));

    if (blockIdx.x == 0) {
        const int q = threadIdx.x;

        float avg2  = (float)counts[q] * (1.0f / 65536.0f);
        float pnew2 = __fadd_rn(__fmul_rn(embed_prob[q], 0.99f),
                                __fmul_rn(0.01f, avg2));
        out_prob[q] = pnew2;

        float term = __fmul_rn(avg2, logf(__fadd_rn(avg2, 1e-10f)));
        __shared__ double red[1024];
        red[q] = (double)term;
        __syncthreads();
        for (int st = 512; st; st >>= 1) {
            if (q < st) red[q] += red[q + st];
            __syncthreads();
        }
        if (q == 0) {
            float s32 = (float)red[0];
            out_perp[0] = expf(-s32);
            double lm = loss_acc[0] / 4194304.0;
            float  m  = (float)lm;
            out_loss[0] = __fadd_rn(__fmul_rn(0.25f, m), m);  // BETA*m + m
        }
    }
}

extern "C" void kernel_launch(void* const* d_in, const int* in_sizes, int n_in,
                              void* d_out, int out_size, void* d_ws, size_t ws_size,
                              hipStream_t stream) {
    const float* z    = (const float*)d_in[0];   // 16*64*64*64
    const float* emb  = (const float*)d_in[1];   // 1024*64
    const float* prob = (const float*)d_in[2];   // 1024

    float* out        = (float*)d_out;
    float* out_zq     = out;                 // 4194304
    float* out_loss   = out + 4194304;       // 1
    float* out_perp   = out + 4194305;       // 1
    float* out_newemb = out + 4194306;       // 65536
    float* out_prob   = out + 4259842;       // 1024
    float* out_idx    = out + 4260866;       // 65536

    char* ws = (char*)d_ws;
    unsigned long long* wsrow = (unsigned long long*)(ws + WS_ROW);
    unsigned long long* wscol = (unsigned long long*)(ws + WS_COL);
    unsigned int*       cnts  = (unsigned int*)(ws + WS_CNT);
    double*             lacc  = (double*)(ws + WS_LOSS);
    float*              en2   = (float*)(ws + WS_EN2);

    hipMemsetAsync(d_ws, 0, WS_BYTES, stream);

    hipLaunchKernelGGL(k_en2, dim3(4), dim3(256), 0, stream, emb, en2);
    hipLaunchKernelGGL(k_scores, dim3(256, KP), dim3(256), 0, stream,
                       z, emb, en2, wsrow, wscol);
    hipLaunchKernelGGL(k_tokens, dim3(256), dim3(256), 0, stream,
                       z, emb, wsrow, cnts, lacc, out_zq, out_idx);
    hipLaunchKernelGGL(k_tail, dim3(64), dim3(1024), 0, stream,
                       z, emb, prob, wscol, cnts, lacc,
                       out_newemb, out_loss, out_perp, out_prob);
}

// Round 2
// 260.327 us; speedup vs baseline: 1.0513x; 1.0513x over previous
//
#include <hip/hip_runtime.h>

// VectorQuantiser forward, MI355X fp32.
// N=65536 tokens (16x64x64, channel dim 64 strided by 4096), K=1024 codes, D=64.
//
// Round 4: z residency forced via asm volatile memory clobber placed AFTER the
// 64 z loads. Round-3's register pin ("+v") was satisfied through AGPRs on the
// unified file (ArchVGPR stayed 52, dur +10us from accvgpr copies); the memory
// clobber instead makes re-materializing the z loads ILLEGAL (the asm may have
// written z), so the values must stay in registers the allocator actually
// feeds to v_fma. Round-2/3 counters (VGPR=52, VALUBusy~42%, 0 bank conflicts,
// HBM ~1%) showed the inner loop was ~64 per-lane L1 dword reloads + 64 FMAs
// per code -> TA-issue-bound. e-rows stay on the s_load path (SGPR=112 shows
// uniformity analysis works). All rounding-sensitive fp ops bit-identical.

#define KP 4

// ---- ws layout (bytes) ----
#define WS_ROW   0        // u64 wsrow[65536]  packed (ord(d)<<32)|~k
#define WS_COL   524288   // u64 wscol[1024]   packed (ord(d)<<32)|~n
#define WS_CNT   532480   // u32 counts[1024]
#define WS_LOSS  536576   // double loss_acc
#define WS_EN2   536592   // float en2[1024]
#define WS_BYTES 540688

__device__ __forceinline__ unsigned int f32_ord(float x) {
    unsigned int b = __float_as_uint(x);
    return (b & 0x80000000u) ? ~b : (b | 0x80000000u);
}

// numpy pairwise sum of squares over 64 contiguous values (8 strided chains,
// then ((r0+r1)+(r2+r3))+((r4+r5)+(r6+r7))), fp32, no contraction.
template <typename F>
__device__ __forceinline__ float np_pairwise64_sq(F get) {
    float r[8];
#pragma unroll
    for (int j = 0; j < 8; ++j) {
        float v = get(j);
        r[j] = __fmul_rn(v, v);
    }
#pragma unroll
    for (int i = 8; i < 64; i += 8) {
#pragma unroll
        for (int j = 0; j < 8; ++j) {
            float v = get(i + j);
            r[j] = __fadd_rn(r[j], __fmul_rn(v, v));
        }
    }
    return __fadd_rn(__fadd_rn(__fadd_rn(r[0], r[1]), __fadd_rn(r[2], r[3])),
                     __fadd_rn(__fadd_rn(r[4], r[5]), __fadd_rn(r[6], r[7])));
}

// ---- K0: codebook squared norms ----
__global__ __launch_bounds__(256) void k_en2(const float* __restrict__ emb,
                                             float* __restrict__ en2) {
    int k = blockIdx.x * 256 + threadIdx.x;
    const float* a = emb + (size_t)k * 64;
    en2[k] = np_pairwise64_sq([&](int i) { return a[i]; });
}

// ---- K1: score matrix + row/col argmax ----
// grid (256 token-blocks, KP code-partitions), block 256 = 4 waves.
// Thread = 1 token (z held in 64 VGPRs, enforced by the memory clobber).
// Embedding reads wave-uniform -> s_load feeds v_fma as the SGPR operand.
// Column argmax: per-wave LDS tile [64 tokens][32 codes], stride 33.
__global__ __launch_bounds__(256, 3) void k_scores(
    const float* __restrict__ z, const float* __restrict__ emb,
    const float* __restrict__ en2,
    unsigned long long* __restrict__ wsrow,
    unsigned long long* __restrict__ wscol) {
    const int t    = threadIdx.x;
    const int lane = t & 63;
    const int wave = t >> 6;
    const int n    = blockIdx.x * 256 + t;
    const int k0   = blockIdx.y * 256;
    const int b    = n >> 12;
    const int hw   = n & 4095;

    __shared__ float tile[4][64 * 33];            // 33792 B, per-wave slabs
    __shared__ unsigned long long kbuf[4][32];    // 1 KB

    const float* zp = z + (size_t)b * 262144 + hw;
    float zr[64];
#pragma unroll
    for (int c = 0; c < 64; ++c) zr[c] = zp[(size_t)c * 4096];
    // The asm may have written z: re-materializing any zp[] load below this
    // point is now illegal, so all 64 values must be carried in registers
    // across the whole code loop. (Round-2/3: compiler sank the loads into
    // the inner loop -> ~64 L1 reloads per code, VALUBusy 42%.)
    asm volatile("" ::: "memory");

    const float nzn2 = -np_pairwise64_sq([&](int i) { return zr[i]; });

    float bestv = -3.4e38f;
    int   bestk = k0;

    const float4* E4 = reinterpret_cast<const float4*>(emb);
    float* mytile = tile[wave];

    for (int g = 0; g < 8; ++g) {
        const int kg = k0 + g * 32;

        for (int kk = 0; kk < 32; ++kk) {
            const int k = kg + kk;
            const float4* ek = E4 + (size_t)k * 16;   // wave-uniform -> s_load
            float c0 = 0.f, c1 = 0.f, c2 = 0.f, c3 = 0.f;
#pragma unroll
            for (int j = 0; j < 16; ++j) {
                float4 e = ek[j];
                c0 = fmaf(e.x, zr[4 * j + 0], c0);
                c1 = fmaf(e.y, zr[4 * j + 1], c1);
                c2 = fmaf(e.z, zr[4 * j + 2], c2);
                c3 = fmaf(e.w, zr[4 * j + 3], c3);
            }
            float dot = (c0 + c1) + (c2 + c3);
            // d = ((-zn2) - en2) + 2*dot, per-op fp32 like numpy
            float d = __fadd_rn(__fsub_rn(nzn2, en2[k]), 2.0f * dot);

            // row argmax: ascending k, strict > == first-index ties
            if (d > bestv) { bestv = d; bestk = k; }

            // stash for column reduction: bank (lane+kk)&31 -> 2-way, free
            mytile[lane * 33 + kk] = d;
        }
        __syncthreads();  // also orders tile writes vs cross-lane reads

        // column reduce: lane owns code c=lane&31, half h=lane>>5 (32 tokens)
        {
            const int c = lane & 31, h = lane >> 5;
            const float* col = mytile + (h * 32) * 33 + c;
            float bv = col[0];
            int   bt = 0;
#pragma unroll
            for (int tt = 1; tt < 32; ++tt) {
                float v = col[(size_t)tt * 33];
                if (v > bv) { bv = v; bt = tt; }   // ascending token, strict >
            }
            int nwin = blockIdx.x * 256 + wave * 64 + h * 32 + bt;
            unsigned long long key =
                ((unsigned long long)f32_ord(bv) << 32) |
                (unsigned long long)(unsigned int)(~(unsigned int)nwin);
            unsigned long long other = __shfl_xor(key, 32, 64);
            if (other > key) key = other;          // ties: larger key = smaller n
            if (h == 0) kbuf[wave][c] = key;
        }
        __syncthreads();
        if (t < 32) {
            unsigned long long m = kbuf[0][t];
#pragma unroll
            for (int w = 1; w < 4; ++w) {
                unsigned long long o = kbuf[w][t];
                m = (o > m) ? o : m;
            }
            atomicMax(&wscol[kg + t], m);
        }
        __syncthreads();
    }

    unsigned long long rowkey =
        ((unsigned long long)f32_ord(bestv) << 32) |
        (unsigned long long)(unsigned int)(~(unsigned int)bestk);
    atomicMax(&wsrow[n], rowkey);
}

// ---- K2: per-token outputs: z_q (straight-through), indices, hist, loss ----
__global__ __launch_bounds__(256) void k_tokens(
    const float* __restrict__ z, const float* __restrict__ emb,
    const unsigned long long* __restrict__ wsrow,
    unsigned int* __restrict__ counts, double* __restrict__ loss_acc,
    float* __restrict__ out_zq, float* __restrict__ out_idx) {
    const int n  = blockIdx.x * 256 + threadIdx.x;
    const int b  = n >> 12;
    const int hw = n & 4095;

    unsigned long long key = wsrow[n];
    int idx = (int)(~(unsigned int)(key & 0xFFFFFFFFull));
    out_idx[n] = (float)idx;
    atomicAdd(&counts[idx], 1u);

    const float* zp = z + (size_t)b * 262144 + hw;
    float*       op = out_zq + (size_t)b * 262144 + hw;
    const float* ep = emb + (size_t)idx * 64;

    double ls = 0.0;
#pragma unroll
    for (int c = 0; c < 64; ++c) {
        float zc   = zp[(size_t)c * 4096];
        float eq   = ep[c];
        float diff = __fsub_rn(eq, zc);              // fl(z_q - zc)
        float sq   = __fmul_rn(diff, diff);
        ls += (double)sq;
        op[(size_t)c * 4096] = __fadd_rn(zc, diff);  // zc + fl(z_q - zc)
    }

    __shared__ double sred[256];
    sred[threadIdx.x] = ls;
    __syncthreads();
    for (int st = 128; st; st >>= 1) {
        if (threadIdx.x < st) sred[threadIdx.x] += sred[threadIdx.x + st];
        __syncthreads();
    }
    if (threadIdx.x == 0) atomicAdd(loss_acc, sred[0]);
}

// ---- K3: tail — new embedding (all blocks) + scalars (block 0 only) ----
// grid 64 x 1024 threads. newemb: thread = (code, channel), 16 codes/block.
// Block 0 additionally computes loss/perplexity/embed_prob (former k_scalars,
// code copied verbatim -> bit-identical).
__global__ __launch_bounds__(1024) void k_tail(
    const float* __restrict__ z, const float* __restrict__ emb,
    const float* __restrict__ embed_prob,
    const unsigned long long* __restrict__ wscol,
    const unsigned int* __restrict__ counts,
    const double* __restrict__ loss_acc,
    float* __restrict__ out_newemb, float* __restrict__ out_loss,
    float* __restrict__ out_perp, float* __restrict__ out_prob) {
    const int k = blockIdx.x * 16 + (threadIdx.x >> 6);
    const int c = threadIdx.x & 63;

    // recompute pnew/decay with ops identical to the scalars path (bit-equal)
    float avg  = (float)counts[k] * (1.0f / 65536.0f);
    float pnew = __fadd_rn(__fmul_rn(embed_prob[k], 0.99f),
                           __fmul_rn(0.01f, avg));
    float tt = __fdiv_rn(__fmul_rn(__fmul_rn(pnew, 1024.0f), 10.0f), 0.01f);
    float dk = expf(__fsub_rn(-tt, 1e-3f));
    float omd = __fsub_rn(1.0f, dk);

    unsigned long long ck = wscol[k];
    int cn  = (int)(~(unsigned int)(ck & 0xFFFFFFFFull));
    int cb  = cn >> 12;
    int chw = cn & 4095;

    float rf = z[(size_t)cb * 262144 + (size_t)c * 4096 + chw];
    float e  = emb[(size_t)k * 64 + c];
    out_newemb[(size_t)k * 64 + c] =
        __fadd_rn(__fmul_rn(e, omd), __fmul_rn(rf, dk));

    if (blockIdx.x == 0) {
        const int q = threadIdx.x;

        float avg2  = (float)counts[q] * (1.0f / 65536.0f);
        float pnew2 = __fadd_rn(__fmul_rn(embed_prob[q], 0.99f),
                                __fmul_rn(0.01f, avg2));
        out_prob[q] = pnew2;

        float term = __fmul_rn(avg2, logf(__fadd_rn(avg2, 1e-10f)));
        __shared__ double red[1024];
        red[q] = (double)term;
        __syncthreads();
        for (int st = 512; st; st >>= 1) {
            if (q < st) red[q] += red[q + st];
            __syncthreads();
        }
        if (q == 0) {
            float s32 = (float)red[0];
            out_perp[0] = expf(-s32);
            double lm = loss_acc[0] / 4194304.0;
            float  m  = (float)lm;
            out_loss[0] = __fadd_rn(__fmul_rn(0.25f, m), m);  // BETA*m + m
        }
    }
}

extern "C" void kernel_launch(void* const* d_in, const int* in_sizes, int n_in,
                              void* d_out, int out_size, void* d_ws, size_t ws_size,
                              hipStream_t stream) {
    const float* z    = (const float*)d_in[0];   // 16*64*64*64
    const float* emb  = (const float*)d_in[1];   // 1024*64
    const float* prob = (const float*)d_in[2];   // 1024

    float* out        = (float*)d_out;
    float* out_zq     = out;                 // 4194304
    float* out_loss   = out + 4194304;       // 1
    float* out_perp   = out + 4194305;       // 1
    float* out_newemb = out + 4194306;       // 65536
    float* out_prob   = out + 4259842;       // 1024
    float* out_idx    = out + 4260866;       // 65536

    char* ws = (char*)d_ws;
    unsigned long long* wsrow = (unsigned long long*)(ws + WS_ROW);
    unsigned long long* wscol = (unsigned long long*)(ws + WS_COL);
    unsigned int*       cnts  = (unsigned int*)(ws + WS_CNT);
    double*             lacc  = (double*)(ws + WS_LOSS);
    float*              en2   = (float*)(ws + WS_EN2);

    hipMemsetAsync(d_ws, 0, WS_BYTES, stream);

    hipLaunchKernelGGL(k_en2, dim3(4), dim3(256), 0, stream, emb, en2);
    hipLaunchKernelGGL(k_scores, dim3(256, KP), dim3(256), 0, stream,
                       z, emb, en2, wsrow, wscol);
    hipLaunchKernelGGL(k_tokens, dim3(256), dim3(256), 0, stream,
                       z, emb, wsrow, cnts, lacc, out_zq, out_idx);
    hipLaunchKernelGGL(k_tail, dim3(64), dim3(1024), 0, stream,
                       z, emb, prob, wscol, cnts, lacc,
                       out_newemb, out_loss, out_perp, out_prob);
}